// Round 19
// baseline (63.611 us; speedup 1.0000x reference)
//
#include <hip/hip_runtime.h>
#include <hip/hip_bf16.h>
#include <stdint.h>

#define N_ATOMS 131072
#define D_IN    128
#define D_HID   256
#define N_ELEM  4
#define K4_BLOCKS 512                      // (hhalf via bit3) x 256 q-stripes

typedef __attribute__((ext_vector_type(8))) short bf16x8;
typedef __attribute__((ext_vector_type(4))) float f32x4;

// ws layout (bytes):
//   [0,       262144): W1t bf16 [4][256][128] (h-major, k contiguous)
//   [262272,  278656): bpart[4096] float (per-wave partials)
#define WS_BPART  262272

__device__ __forceinline__ unsigned short f2bf_rne(float f) {
    union { float f; unsigned u; } v; v.f = f;
    unsigned r = v.u + 0x7FFFu + ((v.u >> 16) & 1u);   // RNE
    return (unsigned short)(r >> 16);
}

__device__ __forceinline__ bf16x8 cvt8(f32x4 v0, f32x4 v1) {
    uint4 o;
    o.x = (__float_as_uint(v0[0]) >> 16) | (__float_as_uint(v0[1]) & 0xFFFF0000u);
    o.y = (__float_as_uint(v0[2]) >> 16) | (__float_as_uint(v0[3]) & 0xFFFF0000u);
    o.z = (__float_as_uint(v1[0]) >> 16) | (__float_as_uint(v1[1]) & 0xFFFF0000u);
    o.w = (__float_as_uint(v1[2]) >> 16) | (__float_as_uint(v1[3]) & 0xFFFF0000u);
    return __builtin_bit_cast(bf16x8, o);
}

// K1: W1 [4][128][256] -> W1t bf16 [4][256][128] via LDS 64x64 tile transpose.
__global__ void tnn_k1_w1t(const float* __restrict__ W1, unsigned short* __restrict__ W1t) {
    __shared__ float tile[64][65];
    int b  = blockIdx.x;
    int e  = b >> 3;
    int k0 = ((b >> 2) & 1) * 64;
    int h0 = (b & 3) * 64;
    int t  = threadIdx.x;
    int cg = t & 15;
    int rr = t >> 4;
    const float* src = W1 + ((size_t)e * D_IN + k0) * D_HID + h0;
    #pragma unroll
    for (int j = 0; j < 4; ++j) {
        int row = rr + j * 16;
        f32x4 v = *(const f32x4*)(src + (size_t)row * D_HID + cg * 4);
        tile[row][cg * 4 + 0] = v[0];
        tile[row][cg * 4 + 1] = v[1];
        tile[row][cg * 4 + 2] = v[2];
        tile[row][cg * 4 + 3] = v[3];
    }
    __syncthreads();
    unsigned short* dst = W1t + ((size_t)e * D_HID + h0) * D_IN + k0;
    #pragma unroll
    for (int j = 0; j < 4; ++j) {
        int hrow = rr + j * 16;
        ushort4 o;
        o.x = f2bf_rne(tile[cg * 4 + 0][hrow]);
        o.y = f2bf_rne(tile[cg * 4 + 1][hrow]);
        o.z = f2bf_rne(tile[cg * 4 + 2][hrow]);
        o.w = f2bf_rne(tile[cg * 4 + 3][hrow]);
        *(ushort4*)(dst + (size_t)hrow * D_IN + cg * 4) = o;
    }
}

// K4: NO sorting. Block = (h-half, 512-atom stripe in NATURAL order). Stages
// all 4 experts' W1t h-half (128 KB LDS, k-major, 1 block/CU). Wave holds 64
// atoms' A-frags in regs across the nt loop; per nt computes all 4 experts'
// MFMAs and selects acc/b1/w2 per row by eid (cndmask chains) before ONE tanh.
// All X/eid reads are sequential streams. b2 bias folded per-atom (hh==0).
__global__ __launch_bounds__(512, 2) void tnn_k4_mlp(
        const float* __restrict__ X, const int* __restrict__ eid,
        const unsigned short* __restrict__ W1t, const float* __restrict__ b1,
        const float* __restrict__ W2, const float* __restrict__ b2,
        float* __restrict__ bpart) {
    __shared__ unsigned char ldsB[131072];   // [4e][16 kblk][128 h][16 B]
    const float C2 = 2.8853900817779268f;    // 2*log2(e)

    int t = threadIdx.x;
    int wid  = t >> 6;                        // 0..7
    int lane = t & 63;
    int l15  = lane & 15;
    int lk   = lane >> 4;
    int b    = blockIdx.x;
    int hh   = (b >> 3) & 1;                  // h-half; pair (b, b+8) same XCD
    int q    = (b & 7) | ((b >> 4) << 3);     // 0..255 stripe id

    // ---- stage B: thread t = (e = t>>7, hloc = t&127); 16 x 16B writes ----
    {
        int e = t >> 7, hloc = t & 127;
        const unsigned short* src = W1t + ((size_t)e * D_HID + hh * 128 + hloc) * D_IN;
        unsigned char* dst = ldsB + e * 32768 + hloc * 16;
        #pragma unroll
        for (int kb = 0; kb < 16; ++kb)
            *(bf16x8*)(dst + kb * 2048) = *(const bf16x8*)(src + kb * 8);
    }

    int base = q * 512 + wid * 64;           // this wave's 64 atoms

    // ---- A: 4 subtiles x 16 rows, sequential loads, bf16 in regs (64 VGPR) ----
    bf16x8 a[4][4];
    int4 e4[4];
    #pragma unroll
    for (int s = 0; s < 4; ++s) {
        const float* xr = X + (size_t)(base + s * 16 + l15) * D_IN + lk * 8;
        f32x4 raw[8];
        #pragma unroll
        for (int ks = 0; ks < 4; ++ks) {
            raw[2 * ks]     = *(const f32x4*)(xr + ks * 32);
            raw[2 * ks + 1] = *(const f32x4*)(xr + ks * 32 + 4);
        }
        #pragma unroll
        for (int ks = 0; ks < 4; ++ks)
            a[s][ks] = cvt8(raw[2 * ks], raw[2 * ks + 1]);
        e4[s] = *(const int4*)(eid + base + s * 16 + lk * 4);
    }

    float partial = 0.f;
    if (hh == 0 && l15 == 0) {               // b2 bias, once per atom
        float4 b2v = *(const float4*)b2;
        #pragma unroll
        for (int s = 0; s < 4; ++s) {
            int er[4] = {e4[s].x, e4[s].y, e4[s].z, e4[s].w};
            #pragma unroll
            for (int r = 0; r < 4; ++r) {
                float v = (er[r] == 1) ? b2v.y : b2v.x;
                v = (er[r] == 2) ? b2v.z : v;
                v = (er[r] == 3) ? b2v.w : v;
                partial += v;
            }
        }
    }

    __syncthreads();                          // B staged

    const float* b1g = b1 + hh * 128 + l15;   // + e*256 + nt*16
    const float* w2g = W2 + hh * 128 + l15;

    #pragma unroll 1
    for (int nt = 0; nt < 8; ++nt) {
        // cur B for 4 experts x 4 k-slices (16 ds_read_b128, serves 64 atoms)
        bf16x8 cur[4][4];
        unsigned off = (unsigned)lk * 2048u + (unsigned)l15 * 16u + (unsigned)nt * 256u;
        #pragma unroll
        for (int e = 0; e < 4; ++e)
            #pragma unroll
            for (int ks = 0; ks < 4; ++ks)
                cur[e][ks] = *(const bf16x8*)(ldsB + (unsigned)e * 32768u + (unsigned)ks * 8192u + off);

        float bx0 = b1g[nt * 16], bx1 = b1g[nt * 16 + D_HID],
              bx2 = b1g[nt * 16 + 2 * D_HID], bx3 = b1g[nt * 16 + 3 * D_HID];
        float by0 = w2g[nt * 16], by1 = w2g[nt * 16 + D_HID],
              by2 = w2g[nt * 16 + 2 * D_HID], by3 = w2g[nt * 16 + 3 * D_HID];

        #pragma unroll
        for (int s = 0; s < 4; ++s) {
            f32x4 acc[4];
            #pragma unroll
            for (int e = 0; e < 4; ++e) {
                acc[e] = f32x4{0.f, 0.f, 0.f, 0.f};
                #pragma unroll
                for (int ks = 0; ks < 4; ++ks)
                    acc[e] = __builtin_amdgcn_mfma_f32_16x16x32_bf16(a[s][ks], cur[e][ks], acc[e], 0, 0, 0);
            }
            int er[4] = {e4[s].x, e4[s].y, e4[s].z, e4[s].w};
            #pragma unroll
            for (int r = 0; r < 4; ++r) {
                float sel = (er[r] == 1) ? acc[1][r] : acc[0][r];
                sel = (er[r] == 2) ? acc[2][r] : sel;
                sel = (er[r] == 3) ? acc[3][r] : sel;
                float bx = (er[r] == 1) ? bx1 : bx0;
                bx = (er[r] == 2) ? bx2 : bx;
                bx = (er[r] == 3) ? bx3 : bx;
                float by = (er[r] == 1) ? by1 : by0;
                by = (er[r] == 2) ? by2 : by;
                by = (er[r] == 3) ? by3 : by;
                // tanh(p) = 1 - 2/(exp2(C2*p)+1)
                float ev = __builtin_amdgcn_exp2f((sel + bx) * C2);
                float rc = __builtin_amdgcn_rcpf(ev + 1.f);
                partial = fmaf(by, fmaf(-2.f, rc, 1.f), partial);
            }
        }
    }

    #pragma unroll
    for (int o = 32; o; o >>= 1)
        partial += __shfl_down(partial, o);
    if (lane == 0) bpart[b * 8 + wid] = partial;   // plain store
}

// K5: fixed-order reduce of 4096 per-wave partials (bias already in K4).
__global__ void tnn_k5_reduce(const float* __restrict__ bpart, float* __restrict__ out) {
    __shared__ float r[4];
    int t = threadIdx.x;
    float s = 0.f;
    #pragma unroll
    for (int j = 0; j < 16; ++j) s += bpart[j * 256 + t];
    #pragma unroll
    for (int o = 32; o; o >>= 1)
        s += __shfl_down(s, o);
    if ((t & 63) == 0) r[t >> 6] = s;
    __syncthreads();
    if (t == 0) out[0] = r[0] + r[1] + r[2] + r[3];
}

extern "C" void kernel_launch(void* const* d_in, const int* in_sizes, int n_in,
                              void* d_out, int out_size, void* d_ws, size_t ws_size,
                              hipStream_t stream) {
    const float* X   = (const float*)d_in[0];
    const int*   eid = (const int*)  d_in[1];
    const float* W1  = (const float*)d_in[2];
    const float* b1  = (const float*)d_in[3];
    const float* W2  = (const float*)d_in[4];
    const float* b2  = (const float*)d_in[5];
    float* out = (float*)d_out;

    char* ws = (char*)d_ws;
    unsigned short* W1t = (unsigned short*)ws;
    float* bpart = (float*)(ws + WS_BPART);

    hipLaunchKernelGGL(tnn_k1_w1t,    dim3(32),        dim3(256), 0, stream, W1, W1t);
    hipLaunchKernelGGL(tnn_k4_mlp,    dim3(K4_BLOCKS), dim3(512), 0, stream,
                       X, eid, W1t, b1, W2, b2, bpart);
    hipLaunchKernelGGL(tnn_k5_reduce, dim3(1),         dim3(256), 0, stream, bpart, out);
}